// Round 2
// baseline (11052.779 us; speedup 1.0000x reference)
//
#include <hip/hip_runtime.h>
#include <math.h>

// Speller round 9: 2 WGs/CU — hide barrier latency with co-resident groups.
//   v8 post-mortem: redundant combine (bulk sc1 gathers) costs MORE than the
//   barrier it removed (FETCH +147MB, +2us/step). Reverted to v7 protocol.
//   v7 counters: occupancy 24.4% = 1 WG/CU -> every flag-poll wait is fully
//   exposed. v9 halves LDS per WG so TWO WGs co-reside per CU:
//     attn: 16 groups x 32 WGs, 2 batches/group, x_s = 32 slots  (dyn 71.7KB)
//     lstm:  8 groups x 64 WGs, u-slice 8, R_s = 32 cols         (dyn 74.3KB)
//   512 blocks / 256 CUs -> co-resident pair (bid, bid+256) = DIFFERENT
//   groups: one group's poll overlaps the other's compute. Per-WG compute
//   also halves. LDS GEMV operands use kh*129 chunk padding (4 k-quarters)
//   to stay bank-conflict-free.

#define U_   512
#define S_   512
#define T_   128
#define B_   32
#define G4   2048
#define V_   46
#define FSTR 32            // flag stride in u32 = 128 B

#define AT_LD(p)     __hip_atomic_load((p), __ATOMIC_RELAXED, __HIP_MEMORY_SCOPE_AGENT)
#define AT_ST(p, v)  __hip_atomic_store((p), (v), __ATOMIC_RELAXED, __HIP_MEMORY_SCOPE_AGENT)

// 1-hop barrier over the NW WGs of this group. gflags = NW padded slots.
template <int NW>
__device__ __forceinline__ void group_bar(unsigned* gflags, unsigned seq,
                                          int wgid) {
  __syncthreads();   // all waves' stores drained (vmcnt) before arrival
  const int tid = threadIdx.x;
  if (tid < NW) {
    if (tid == 0)
      AT_ST(&gflags[wgid * FSTR], seq);
    while (!__all(AT_LD(&gflags[tid * FSTR]) >= seq))
      __builtin_amdgcn_s_sleep(1);
  }
  __syncthreads();
}

// ---------------- GEMM: Z[M,2048] = A[M,512] @ W[512,2048] + b ----------------
__global__ __launch_bounds__(256) void gemm_k512(
    const float* __restrict__ A, const float* __restrict__ W,
    const float* __restrict__ b, float* __restrict__ Z) {
  const int tid = threadIdx.x;
  const int j = blockIdx.x * 1024 + tid * 4;
  const int i0 = blockIdx.y * 8;
  float4 bj = *(const float4*)(b + j);
  float4 acc[8];
#pragma unroll
  for (int r = 0; r < 8; ++r) acc[r] = bj;
  const float* Arow = A + (size_t)i0 * U_;
  for (int k = 0; k < U_; ++k) {
    float4 w = *(const float4*)(W + (size_t)k * G4 + j);
#pragma unroll
    for (int r = 0; r < 8; ++r) {
      float a = Arow[(size_t)r * U_ + k];
      acc[r].x = fmaf(a, w.x, acc[r].x);
      acc[r].y = fmaf(a, w.y, acc[r].y);
      acc[r].z = fmaf(a, w.z, acc[r].z);
      acc[r].w = fmaf(a, w.w, acc[r].w);
    }
  }
#pragma unroll
  for (int r = 0; r < 8; ++r)
    *(float4*)(Z + (size_t)(i0 + r) * G4 + j) = acc[r];
}

// ---------------- transpose R[512][2048] -> RT[2048][512] ----------------
__global__ __launch_bounds__(256) void transpose_R(
    const float* __restrict__ R, float* __restrict__ RT) {
  __shared__ float tile[64][65];
  const int c0 = blockIdx.x * 64, k0 = blockIdx.y * 64;
  const int tc = threadIdx.x & 63, tr = threadIdx.x >> 6;
  for (int r = tr; r < 64; r += 4)
    tile[r][tc] = R[(size_t)(k0 + r) * G4 + c0 + tc];
  __syncthreads();
  for (int r = tr; r < 64; r += 4)
    RT[(size_t)(c0 + r) * 512 + k0 + tc] = tile[tc][r];
}

// ---------------- attention LSTM: 16 groups x 32 WGs, 2 batches/group ------
// dyn LDS: x_s [512][33] + h_st [2][516] = 71712 B  -> 2 WGs/CU
// hbuf: rotating [T+1][32][512]; hnbuf: rotating [T][32][512]
__global__ __launch_bounds__(512) void attn_coop(
    const float* __restrict__ x, const float* __restrict__ ZY,
    const float* __restrict__ RT, float* __restrict__ ctxs,
    float* hbuf, float* hnbuf, float* smax, float* ssumg,
    float* ctxpart, unsigned* flags) {
  extern __shared__ float dyn[];
  float* x_s  = dyn;                 // [u][33], conflict-free
  float* h_st = dyn + 512 * 33;      // [2][516], k-quarters at kh*129
  __shared__ float zp[2][64][4];
  __shared__ float p_s[32];
  __shared__ float ctx_s[32];

  const int tid = threadIdx.x;
  const int bid = blockIdx.x;
  const int g    = bid >> 5;                      // 0..15
  const int wgid = bid & 31;
  const int u0   = wgid * 16;
  // GEMV role mapping: 64 cols x 2 batches x 4 k-quarters
  const int kh  = tid & 3;
  const int b_l = (tid >> 2) & 1;
  const int col = tid >> 3;                       // 0..63
  const int zcol = (col >> 4) * 512 + u0 + (col & 15);
  // attention role mapping: 16 score slices x 32 slots per batch
  const int b_att = 2 * g + (wgid >> 4);
  const int sc = wgid & 15;
  unsigned* gflags = flags + g * 32 * FSTR;

  for (int idx = tid; idx < 32 * 512; idx += 512) {
    int sl = idx >> 9, u = idx & 511;
    x_s[u * 33 + sl] = x[((size_t)b_att * S_ + sc * 32 + sl) * U_ + u];
  }
  float c = 0.f, hn_reg = 0.f;
  unsigned seq = 0;
  __syncthreads();

  for (int t = 0; t < T_; ++t) {
    // ---- stage h slot t (2 batches, cached float4: virgin rotating lines) --
    if (tid < 256) {
      const float4* hb4 =
          (const float4*)(hbuf + (size_t)t * 16384 + 2 * g * 512);
      float4 v = hb4[tid];
      int b = tid >> 7;             // 0..1
      int kk4 = (tid & 127) * 4;    // 0..508
      *(float4*)(h_st + b * 516 + (kk4 >> 7) * 129 + (kk4 & 127)) = v;
    }
    __syncthreads();
    // ---- GEMV: z-partial from h(LDS) x RT(L2) ----
    {
      const float4* H4 = (const float4*)(h_st + b_l * 516 + kh * 129);
      const float4* R4 = (const float4*)(RT + (size_t)zcol * 512 + kh * 128);
      float acc = 0.f;
#pragma unroll 8
      for (int i = 0; i < 32; ++i) {
        float4 hv = H4[i];
        float4 rv = R4[i];
        acc = fmaf(hv.x, rv.x, acc); acc = fmaf(hv.y, rv.y, acc);
        acc = fmaf(hv.z, rv.z, acc); acc = fmaf(hv.w, rv.w, acc);
      }
      zp[b_l][col][kh] = acc;
    }
    __syncthreads();
    if (tid < 32) {
      const int bb = tid >> 4, uu = tid & 15;
      const int b = 2 * g + bb, u = u0 + uu;
      const float* zy = ZY + ((size_t)b * T_ + t) * G4 + u;
      float zi = zy[0]    + zp[bb][uu][0]      + zp[bb][uu][1]
                          + zp[bb][uu][2]      + zp[bb][uu][3];
      float zf = zy[512]  + zp[bb][16 + uu][0] + zp[bb][16 + uu][1]
                          + zp[bb][16 + uu][2] + zp[bb][16 + uu][3];
      float zg = zy[1024] + zp[bb][32 + uu][0] + zp[bb][32 + uu][1]
                          + zp[bb][32 + uu][2] + zp[bb][32 + uu][3];
      float zo = zy[1536] + zp[bb][48 + uu][0] + zp[bb][48 + uu][1]
                          + zp[bb][48 + uu][2] + zp[bb][48 + uu][3];
      float ig = 1.f / (1.f + expf(-zi));
      float fg = 1.f / (1.f + expf(-zf));
      float gg = tanhf(zg);
      float og = 1.f / (1.f + expf(-zo));
      c = fg * c + ig * gg;
      hn_reg = og * tanhf(c);
      AT_ST(&hnbuf[(size_t)t * 16384 + b * 512 + u], hn_reg);
    }
    group_bar<32>(gflags, ++seq, wgid);             // BAR1: hn complete

    // ---- scores, local softmax, ctx partials (32 slots/WG) ----
    {
      const int wv = tid >> 6, ln = tid & 63;
      // hn read once into regs (rotating slot -> virgin cached lines)
      const float* hnb = hnbuf + (size_t)t * 16384 + b_att * 512;
      float hreg[8];
#pragma unroll
      for (int k = 0; k < 8; ++k) hreg[k] = hnb[ln + 64 * k];
      for (int si = 0; si < 4; ++si) {
        const int sl = wv * 4 + si;
        float a = 0.f;
#pragma unroll
        for (int k = 0; k < 8; ++k)
          a = fmaf(hreg[k], x_s[(ln + 64 * k) * 33 + sl], a);
#pragma unroll
        for (int off = 32; off; off >>= 1) a += __shfl_down(a, off);
        if (ln == 0) p_s[sl] = a;
      }
    }
    __syncthreads();
    if (tid < 32) {
      float v = p_s[tid];
      float m = v;
#pragma unroll
      for (int off = 16; off; off >>= 1) m = fmaxf(m, __shfl_down(m, off));
      m = __shfl(m, 0);
      float ex = expf(v - m);
      p_s[tid] = ex;
      float sm = ex;
#pragma unroll
      for (int off = 16; off; off >>= 1) sm += __shfl_down(sm, off);
      if (tid == 0) {
        AT_ST(&smax[b_att * 16 + sc], m);
        AT_ST(&ssumg[b_att * 16 + sc], sm);
      }
    }
    __syncthreads();
    {
      float a = 0.f;
      const float* xr = x_s + tid * 33;
#pragma unroll 8
      for (int s = 0; s < 32; ++s) a = fmaf(p_s[s], xr[s], a);
      AT_ST(&ctxpart[((size_t)b_att * 16 + sc) * 512 + tid], a);
    }
    group_bar<32>(gflags, ++seq, wgid);             // BAR2: partials complete

    // ---- combine slices (32 pairs x 16 j, sc1 gathers) ----
    {
      const int j = tid & 15;
      const int pair = tid >> 4;            // 0..31 == gates-thread index
      const int bb = pair >> 4, uu = pair & 15;
      const int b = 2 * g + bb, u = u0 + uu;
      float lm = AT_LD(&smax[b * 16 + j]);
      float ss = AT_LD(&ssumg[b * 16 + j]);
      float cp = AT_LD(&ctxpart[((size_t)b * 16 + j) * 512 + u]);
      float gm = lm;
#pragma unroll
      for (int off = 1; off < 16; off <<= 1)
        gm = fmaxf(gm, __shfl_xor(gm, off));
      float w = expf(lm - gm);
      float st = ss * w, cs = cp * w;
#pragma unroll
      for (int off = 1; off < 16; off <<= 1) {
        st += __shfl_xor(st, off);
        cs += __shfl_xor(cs, off);
      }
      if (j == 0) ctx_s[pair] = cs / st;
    }
    __syncthreads();
    if (tid < 32) {
      const int bb = tid >> 4, uu = tid & 15;
      const int b = 2 * g + bb, u = u0 + uu;
      float ctxv = ctx_s[tid];
      c += ctxv;
      float hcar = hn_reg + ctxv;
      AT_ST(&hbuf[(size_t)(t + 1) * 16384 + b * 512 + u], hcar);
      ctxs[((size_t)b * T_ + t) * U_ + u] = ctxv;
    }
    group_bar<32>(gflags, ++seq, wgid);             // BAR3: h(t+1) complete
  }
}

// ---------------- plain LSTM: 8 groups x 64 WGs, u-slice 8 ----------------
// dyn LDS: R_s [32][516] + h_st [4][516] = 74304 B -> 2 WGs/CU
__global__ __launch_bounds__(512) void lstm_coop(
    const float* __restrict__ Zin, const float* __restrict__ R,
    float* __restrict__ seq_out, float* __restrict__ last_out,
    float* hbuf, unsigned* flags) {
  extern __shared__ float dyn[];
  float* R_s  = dyn;                 // [32 cols][516], k-quarters at kh*129
  float* h_st = dyn + 32 * 516;      // [4][516]
  __shared__ float zp[4][32][4];
  const int tid = threadIdx.x;
  const int bid = blockIdx.x;
  const int g    = bid >> 6;                      // 0..7
  const int wgid = bid & 63;
  const int u0   = wgid * 8;
  const int kh  = tid & 3;
  const int b_l = (tid >> 2) & 3;
  const int col = tid >> 4;                       // 0..31
  unsigned* gflags = flags + g * 64 * FSTR;

  // one-time R slice -> LDS (transposed to [col][k], k-quarter padded)
  for (int idx = tid; idx < 32 * 512; idx += 512) {
    int cc = idx & 31, kk = idx >> 5;
    R_s[cc * 516 + (kk >> 7) * 129 + (kk & 127)] =
        R[(size_t)kk * G4 + (cc >> 3) * 512 + u0 + (cc & 7)];
  }
  float c = 0.f;
  unsigned seq = 0;
  __syncthreads();

  for (int t = 0; t < T_; ++t) {
    {
      const float4* hb4 =
          (const float4*)(hbuf + (size_t)t * 16384 + 4 * g * 512);
      float4 v = hb4[tid];
      int b = tid >> 7;             // 0..3
      int kk4 = (tid & 127) * 4;    // 0..508
      *(float4*)(h_st + b * 516 + (kk4 >> 7) * 129 + (kk4 & 127)) = v;
    }
    __syncthreads();
    {
      const float4* H4 = (const float4*)(h_st + b_l * 516 + kh * 129);
      const float4* R4 = (const float4*)(R_s + col * 516 + kh * 129);
      float acc = 0.f;
#pragma unroll 8
      for (int i = 0; i < 32; ++i) {
        float4 hv = H4[i];
        float4 rv = R4[i];
        acc = fmaf(hv.x, rv.x, acc); acc = fmaf(hv.y, rv.y, acc);
        acc = fmaf(hv.z, rv.z, acc); acc = fmaf(hv.w, rv.w, acc);
      }
      zp[b_l][col][kh] = acc;
    }
    __syncthreads();
    if (tid < 32) {
      const int bb = tid >> 3, uu = tid & 7;
      const int b = 4 * g + bb, u = u0 + uu;
      const float* zy = Zin + ((size_t)b * T_ + t) * G4 + u;
      float zi = zy[0]    + zp[bb][uu][0]      + zp[bb][uu][1]
                          + zp[bb][uu][2]      + zp[bb][uu][3];
      float zf = zy[512]  + zp[bb][8 + uu][0]  + zp[bb][8 + uu][1]
                          + zp[bb][8 + uu][2]  + zp[bb][8 + uu][3];
      float zg = zy[1024] + zp[bb][16 + uu][0] + zp[bb][16 + uu][1]
                          + zp[bb][16 + uu][2] + zp[bb][16 + uu][3];
      float zo = zy[1536] + zp[bb][24 + uu][0] + zp[bb][24 + uu][1]
                          + zp[bb][24 + uu][2] + zp[bb][24 + uu][3];
      float ig = 1.f / (1.f + expf(-zi));
      float fg = 1.f / (1.f + expf(-zf));
      float gg = tanhf(zg);
      float og = 1.f / (1.f + expf(-zo));
      c = fg * c + ig * gg;
      float hv2 = og * tanhf(c);
      AT_ST(&hbuf[(size_t)(t + 1) * 16384 + b * 512 + u], hv2);
      if (seq_out) seq_out[((size_t)b * T_ + t) * U_ + u] = hv2;
      if (last_out && t == T_ - 1) last_out[b * U_ + u] = hv2;
    }
    group_bar<64>(gflags, ++seq, wgid);
  }
}

// ---------------- decoder ----------------
__global__ __launch_bounds__(64) void final_k(
    const float* __restrict__ hT, const float* __restrict__ Wd,
    const float* __restrict__ bd, float* __restrict__ out) {
  const int b = blockIdx.x;
  const int v = threadIdx.x;
  float acc = (v < V_) ? bd[v] : -INFINITY;
  if (v < V_) {
    for (int k = 0; k < U_; ++k)
      acc = fmaf(hT[(size_t)b * U_ + k], Wd[(size_t)k * V_ + v], acc);
  }
  float m = acc;
#pragma unroll
  for (int off = 32; off; off >>= 1) m = fmaxf(m, __shfl_down(m, off));
  m = __shfl(m, 0);
  float e = (v < V_) ? expf(acc - m) : 0.f;
  float s = e;
#pragma unroll
  for (int off = 32; off; off >>= 1) s += __shfl_down(s, off);
  s = __shfl(s, 0);
  if (v < V_) out[(size_t)b * V_ + v] = e / s;
}

extern "C" void kernel_launch(void* const* d_in, const int* in_sizes, int n_in,
                              void* d_out, int out_size, void* d_ws, size_t ws_size,
                              hipStream_t stream) {
  const float* x   = (const float*)d_in[0];
  const float* y   = (const float*)d_in[1];
  const float* W_a = (const float*)d_in[2];
  const float* R_a = (const float*)d_in[3];
  const float* b_a = (const float*)d_in[4];
  const float* W1  = (const float*)d_in[5];
  const float* R1  = (const float*)d_in[6];
  const float* b1  = (const float*)d_in[7];
  const float* W2  = (const float*)d_in[8];
  const float* R2  = (const float*)d_in[9];
  const float* b2  = (const float*)d_in[10];
  const float* Wd  = (const float*)d_in[11];
  const float* bd  = (const float*)d_in[12];
  float* out = (float*)d_out;

  float* ZBUF  = (float*)d_ws;                   // 8388608 f
  float* SEQ   = ZBUF + (size_t)8388608;         // 2097152 f
  float* RT    = SEQ + (size_t)2097152;          // 1048576 f
  float* HROT  = RT + (size_t)1048576;           // 129*16384 = 2113536 f
  float* HNROT = HROT + (size_t)2113536;         // 128*16384 = 2097152 f
  float* SMAX  = HNROT + (size_t)2097152;        // 512 (pad to 1024)
  float* SSUM  = SMAX + 1024;                    // 512 (pad to 1024)
  float* CTXP  = SSUM + 1024;                    // 32*16*512 = 262144
  float* HT    = CTXP + 262144;                  // 16384
  unsigned* BAR = (unsigned*)(HT + 16384);

  // flag regions: attn 16 groups x 32 x FSTR; lstm 8 groups x 64 x FSTR
  const int REGION = 16384;                      // u32 each
  unsigned* FLG_A = BAR;
  unsigned* FLG_1 = BAR + REGION;
  unsigned* FLG_2 = BAR + 2 * REGION;

  const int attn_lds = (512 * 33 + 2 * 516) * 4;    // 71712 B
  const int lstm_lds = (32 * 516 + 4 * 516) * 4;    // 74304 B
  hipFuncSetAttribute((const void*)attn_coop,
                      hipFuncAttributeMaxDynamicSharedMemorySize, attn_lds);
  hipFuncSetAttribute((const void*)lstm_coop,
                      hipFuncAttributeMaxDynamicSharedMemorySize, lstm_lds);

  dim3 ggrid(2, 512);
  hipMemsetAsync(BAR, 0, 3 * REGION * 4, stream);

  gemm_k512<<<ggrid, 256, 0, stream>>>(y, W_a, b_a, ZBUF);
  transpose_R<<<dim3(32, 8), 256, 0, stream>>>(R_a, RT);
  hipMemsetAsync(HROT, 0, 16384 * 4, stream);          // h[0] = 0
  attn_coop<<<512, 512, attn_lds, stream>>>(x, ZBUF, RT, SEQ, HROT, HNROT,
                                            SMAX, SSUM, CTXP, FLG_A);
  gemm_k512<<<ggrid, 256, 0, stream>>>(SEQ, W1, b1, ZBUF);
  hipMemsetAsync(HROT, 0, 16384 * 4, stream);          // h1[0] = 0
  lstm_coop<<<512, 512, lstm_lds, stream>>>(ZBUF, R1, SEQ, nullptr, HROT,
                                            FLG_1);
  gemm_k512<<<ggrid, 256, 0, stream>>>(SEQ, W2, b2, ZBUF);
  hipMemsetAsync(HROT, 0, 16384 * 4, stream);          // h2[0] = 0
  lstm_coop<<<512, 512, lstm_lds, stream>>>(ZBUF, R2, nullptr, HT, HROT,
                                            FLG_2);
  final_k<<<B_, 64, 0, stream>>>(HT, Wd, bd, out);
}

// Round 3
// 7675.128 us; speedup vs baseline: 1.4401x; 1.4401x over previous
//
#include <hip/hip_runtime.h>
#include <math.h>

// Speller round 10: revert attn to v7 + fuse lstm1/lstm2 into a 2-stage pipe.
//   v9 post-mortem: 2 WGs/CU co-residency collapsed (spin contention, 2.7x
//   regression). Protocol tolerates neither more pollers nor bigger groups.
//   v10 keeps v7's attn (2085us, verified) and attacks the serial tail
//   (lstm1 845 + gemm 85 + lstm2 845): ONE kernel, 128 WGs/layer
//   (4 groups x 32 WGs x 8 batches), layer2 runs 1 step behind layer1,
//   consuming h1 via rotating global buffer gated by layer1's group flags.
//   Layer2's input GEMV (h1@W2T, streamed from L2 like attn's RT) is folded
//   in and placed between its own arrive/wait so the recurrence-barrier RTT
//   hides behind ~2.5us of independent compute. WG count/protocol = v7.

#define U_   512
#define S_   512
#define T_   128
#define B_   32
#define G4   2048
#define V_   46
#define NWG  256
#define FSTR 32            // flag stride in u32 = 128 B

#define AT_LD(p)     __hip_atomic_load((p), __ATOMIC_RELAXED, __HIP_MEMORY_SCOPE_AGENT)
#define AT_ST(p, v)  __hip_atomic_store((p), (v), __ATOMIC_RELAXED, __HIP_MEMORY_SCOPE_AGENT)

// 1-hop barrier over the 32 WGs of this group. gflags = 32 padded slots.
__device__ __forceinline__ void group_bar(unsigned* gflags, unsigned seq,
                                          int wgid) {
  __syncthreads();   // all waves' stores drained (vmcnt) before arrival
  const int tid = threadIdx.x;
  if (tid < 32) {
    if (tid == 0)
      AT_ST(&gflags[wgid * FSTR], seq);
    while (!__all(AT_LD(&gflags[tid * FSTR]) >= seq))
      __builtin_amdgcn_s_sleep(1);
  }
  __syncthreads();
}

__device__ __forceinline__ void g_wait32(unsigned* gflags, unsigned seq) {
  if (threadIdx.x < 32) {
    while (!__all(AT_LD(&gflags[threadIdx.x * FSTR]) >= seq))
      __builtin_amdgcn_s_sleep(1);
  }
  __syncthreads();
}

__device__ __forceinline__ void g_arrive(unsigned* gflags, unsigned seq,
                                         int wgid) {
  __syncthreads();   // drain stores before flag
  if (threadIdx.x == 0) AT_ST(&gflags[wgid * FSTR], seq);
}

// ---------------- GEMM: Z[M,2048] = A[M,512] @ W[512,2048] + b ----------------
__global__ __launch_bounds__(256) void gemm_k512(
    const float* __restrict__ A, const float* __restrict__ W,
    const float* __restrict__ b, float* __restrict__ Z) {
  const int tid = threadIdx.x;
  const int j = blockIdx.x * 1024 + tid * 4;
  const int i0 = blockIdx.y * 8;
  float4 bj = *(const float4*)(b + j);
  float4 acc[8];
#pragma unroll
  for (int r = 0; r < 8; ++r) acc[r] = bj;
  const float* Arow = A + (size_t)i0 * U_;
  for (int k = 0; k < U_; ++k) {
    float4 w = *(const float4*)(W + (size_t)k * G4 + j);
#pragma unroll
    for (int r = 0; r < 8; ++r) {
      float a = Arow[(size_t)r * U_ + k];
      acc[r].x = fmaf(a, w.x, acc[r].x);
      acc[r].y = fmaf(a, w.y, acc[r].y);
      acc[r].z = fmaf(a, w.z, acc[r].z);
      acc[r].w = fmaf(a, w.w, acc[r].w);
    }
  }
#pragma unroll
  for (int r = 0; r < 8; ++r)
    *(float4*)(Z + (size_t)(i0 + r) * G4 + j) = acc[r];
}

// ---------------- transpose R[512][2048] -> RT[2048][512] ----------------
__global__ __launch_bounds__(256) void transpose_R(
    const float* __restrict__ R, float* __restrict__ RT) {
  __shared__ float tile[64][65];
  const int c0 = blockIdx.x * 64, k0 = blockIdx.y * 64;
  const int tc = threadIdx.x & 63, tr = threadIdx.x >> 6;
  for (int r = tr; r < 64; r += 4)
    tile[r][tc] = R[(size_t)(k0 + r) * G4 + c0 + tc];
  __syncthreads();
  for (int r = tr; r < 64; r += 4)
    RT[(size_t)(c0 + r) * 512 + k0 + tc] = tile[tc][r];
}

// ---------------- attention LSTM: 8 groups x 32 WGs, 4 batches/group ------
// (v7 verbatim — verified 2085us)
// dyn LDS: x_s [512][65] + h_st [4][516]  = 141376 B
// hbuf: rotating [T+1][32][512]; hnbuf: rotating [T][32][512]
__global__ __launch_bounds__(512) void attn_coop(
    const float* __restrict__ x, const float* __restrict__ ZY,
    const float* __restrict__ RT, float* __restrict__ ctxs,
    float* hbuf, float* hnbuf, float* smax, float* ssumg,
    float* ctxpart, unsigned* flags) {
  extern __shared__ float dyn[];
  float* x_s  = dyn;                 // [u][65], conflict-free
  float* h_st = dyn + 512 * 65;      // [b_l][516]
  __shared__ float zp[4][64][2];
  __shared__ float hn_s[512];
  __shared__ float p_s[64];
  __shared__ float ctx_s[64];

  const int tid = threadIdx.x;
  const int bid = blockIdx.x;
  const int g    = bid >> 5;
  const int wgid = bid & 31;
  const int u0   = wgid * 16;
  // GEMV role mapping: 64 cols x 4 batches x 2 k-halves
  const int kh  = tid & 1;
  const int b_l = (tid >> 1) & 3;
  const int col = tid >> 3;                       // 0..63
  const int zcol = (col >> 4) * 512 + u0 + (col & 15);
  // attention role mapping
  const int b_att = 4 * g + (wgid >> 3);
  const int sc = wgid & 7;
  unsigned* gflags = flags + g * 32 * FSTR;

  for (int idx = tid; idx < 64 * 512; idx += 512) {
    int sl = idx >> 9, u = idx & 511;
    x_s[u * 65 + sl] = x[((size_t)b_att * S_ + sc * 64 + sl) * U_ + u];
  }
  float c = 0.f, hn_reg = 0.f;
  unsigned seq = 0;
  __syncthreads();

  for (int t = 0; t < T_; ++t) {
    // ---- stage h slot t (cached float4 burst: virgin lines -> IF$) ----
    {
      const float4* hb4 =
          (const float4*)(hbuf + (size_t)t * 16384 + 4 * g * 512);
      float4 v = hb4[tid];
      *(float4*)(h_st + (tid >> 7) * 516 + (tid & 127) * 4) = v;
    }
    __syncthreads();
    // ---- GEMV: z-partial from h(LDS) x RT(L2) ----
    {
      const float4* H4 = (const float4*)(h_st + b_l * 516 + kh * 256);
      const float4* R4 = (const float4*)(RT + (size_t)zcol * 512 + kh * 256);
      float acc = 0.f;
#pragma unroll 8
      for (int i = 0; i < 64; ++i) {
        float4 hv = H4[i];
        float4 rv = R4[i];
        acc = fmaf(hv.x, rv.x, acc); acc = fmaf(hv.y, rv.y, acc);
        acc = fmaf(hv.z, rv.z, acc); acc = fmaf(hv.w, rv.w, acc);
      }
      zp[b_l][col][kh] = acc;
    }
    __syncthreads();
    if (tid < 64) {
      const int bb = tid >> 4, uu = tid & 15;
      const int b = 4 * g + bb, u = u0 + uu;
      const float* zy = ZY + ((size_t)b * T_ + t) * G4 + u;
      float zi = zy[0]    + zp[bb][uu][0]      + zp[bb][uu][1];
      float zf = zy[512]  + zp[bb][16 + uu][0] + zp[bb][16 + uu][1];
      float zg = zy[1024] + zp[bb][32 + uu][0] + zp[bb][32 + uu][1];
      float zo = zy[1536] + zp[bb][48 + uu][0] + zp[bb][48 + uu][1];
      float ig = 1.f / (1.f + expf(-zi));
      float fg = 1.f / (1.f + expf(-zf));
      float gg = tanhf(zg);
      float og = 1.f / (1.f + expf(-zo));
      c = fg * c + ig * gg;
      hn_reg = og * tanhf(c);
      AT_ST(&hnbuf[(size_t)t * 16384 + b * 512 + u], hn_reg);
    }
    group_bar(gflags, ++seq, wgid);

    // ---- scores, local softmax, ctx partials ----
    if (tid < 128) {
      float4 v = ((const float4*)(hnbuf + (size_t)t * 16384 + b_att * 512))[tid];
      *(float4*)(hn_s + tid * 4) = v;
    }
    __syncthreads();
    {
      const int wv = tid >> 6, ln = tid & 63;
      for (int si = 0; si < 8; ++si) {
        const int sl = wv * 8 + si;
        float a = 0.f;
#pragma unroll
        for (int uu = ln; uu < 512; uu += 64)
          a = fmaf(hn_s[uu], x_s[uu * 65 + sl], a);
#pragma unroll
        for (int off = 32; off; off >>= 1) a += __shfl_down(a, off);
        if (ln == 0) p_s[sl] = a;
      }
    }
    __syncthreads();
    if (tid < 64) {
      float v = p_s[tid];
      float m = v;
#pragma unroll
      for (int off = 32; off; off >>= 1) m = fmaxf(m, __shfl_down(m, off));
      m = __shfl(m, 0);
      float ex = expf(v - m);
      p_s[tid] = ex;
      float sm = ex;
#pragma unroll
      for (int off = 32; off; off >>= 1) sm += __shfl_down(sm, off);
      if (tid == 0) {
        AT_ST(&smax[b_att * 8 + sc], m);
        AT_ST(&ssumg[b_att * 8 + sc], sm);
      }
    }
    __syncthreads();
    {
      float a = 0.f;
      const float* xr = x_s + tid * 65;
#pragma unroll 8
      for (int s = 0; s < 64; ++s) a = fmaf(p_s[s], xr[s], a);
      AT_ST(&ctxpart[((size_t)b_att * 8 + sc) * 512 + tid], a);
    }
    group_bar(gflags, ++seq, wgid);

    // ---- combine slices (parallel over 512 thr: pair x j, sc1 gathers) ----
    {
      const int j = tid & 7;
      const int pair = tid >> 3;            // 0..63 == gates-thread index
      const int bb = pair >> 4, uu = pair & 15;
      const int b = 4 * g + bb, u = u0 + uu;
      float lm = AT_LD(&smax[b * 8 + j]);
      float ss = AT_LD(&ssumg[b * 8 + j]);
      float cp = AT_LD(&ctxpart[((size_t)b * 8 + j) * 512 + u]);
      float gm = lm;
#pragma unroll
      for (int off = 1; off < 8; off <<= 1)
        gm = fmaxf(gm, __shfl_xor(gm, off));
      float w = expf(lm - gm);
      float st = ss * w, cs = cp * w;
#pragma unroll
      for (int off = 1; off < 8; off <<= 1) {
        st += __shfl_xor(st, off);
        cs += __shfl_xor(cs, off);
      }
      if (j == 0) ctx_s[pair] = cs / st;
    }
    __syncthreads();
    if (tid < 64) {
      const int bb = tid >> 4, uu = tid & 15;
      const int b = 4 * g + bb, u = u0 + uu;
      float ctxv = ctx_s[tid];
      c += ctxv;
      float hcar = hn_reg + ctxv;
      AT_ST(&hbuf[(size_t)(t + 1) * 16384 + b * 512 + u], hcar);
      ctxs[((size_t)b * T_ + t) * U_ + u] = ctxv;
    }
    group_bar(gflags, ++seq, wgid);
  }
}

// ---------------- fused 2-layer LSTM pipeline: 256 WGs -------------------
// bid 0..127 = layer1 (4 groups x 32 WGs, 8 batches/group, R1 slice in LDS)
// bid 128..255 = layer2 (same shape), 1 step behind, consuming h1rot gated
// by layer1's flags. Layer2 folds z2 = h1 @ W2T (streamed from L2) into its
// step and hides its recurrence-barrier RTT behind that GEMV.
// dyn LDS: R_s [64][516] + h_st [8][516] = 148608 B -> 1 WG/CU.
__global__ __launch_bounds__(512) void lstm_fused(
    const float* __restrict__ Z1, const float* __restrict__ R1,
    const float* __restrict__ R2, const float* __restrict__ W2T,
    const float* __restrict__ b2, float* h1rot, float* h2rot,
    float* __restrict__ hT, unsigned* fl1, unsigned* fl2) {
  extern __shared__ float dyn[];
  float* R_s  = dyn;               // [64 cols][516]
  float* h_st = dyn + 64 * 516;    // [8 batches][516]
  __shared__ float zp[8][64];

  const int tid = threadIdx.x;
  const int bid = blockIdx.x;
  const int layer = bid >> 7;          // 0 or 1
  const int g     = (bid >> 5) & 3;    // group within layer (8 batches each)
  const int wgid  = bid & 31;
  const int u0    = wgid * 16;
  const int b_l   = tid & 7;           // batch within group
  const int col   = tid >> 3;          // 0..63 (4 gates x 16 u)
  const int zcol  = (col >> 4) * 512 + u0 + (col & 15);
  unsigned* own = (layer ? fl2 : fl1) + g * 32 * FSTR;
  unsigned* in1 = fl1 + g * 32 * FSTR;

  // one-time R slice -> LDS (transposed to [col][k])
  const float* Rm = layer ? R2 : R1;
  for (int idx = tid; idx < 64 * 512; idx += 512) {
    int cc = idx & 63, kk = idx >> 6;
    R_s[cc * 516 + kk] = Rm[(size_t)kk * G4 + (cc >> 4) * 512 + u0 + (cc & 15)];
  }
  float c = 0.f;
  __syncthreads();

  if (layer == 0) {
    for (int t = 0; t < T_; ++t) {
      // stage h1(t): 8 batches x 512 (rotating slot -> virgin cached lines)
      {
        const float4* hb4 =
            (const float4*)(h1rot + (size_t)t * 16384 + (size_t)(8 * g) * 512);
#pragma unroll
        for (int it = 0; it < 2; ++it) {
          int idx = it * 512 + tid;
          float4 v = hb4[idx];
          *(float4*)(h_st + (idx >> 7) * 516 + (idx & 127) * 4) = v;
        }
      }
      __syncthreads();
      {
        const float4* H4 = (const float4*)(h_st + b_l * 516);
        const float4* Rr = (const float4*)(R_s + col * 516);
        float acc = 0.f;
#pragma unroll 8
        for (int i = 0; i < 128; ++i) {
          float4 hv = H4[i];
          float4 rv = Rr[i];
          acc = fmaf(hv.x, rv.x, acc); acc = fmaf(hv.y, rv.y, acc);
          acc = fmaf(hv.z, rv.z, acc); acc = fmaf(hv.w, rv.w, acc);
        }
        zp[b_l][col] = acc;
      }
      __syncthreads();
      if (tid < 128) {
        const int bb = tid >> 4, uu = tid & 15;
        const int b = 8 * g + bb, u = u0 + uu;
        const float* zy = Z1 + ((size_t)b * T_ + t) * G4 + u;
        float zi = zy[0]    + zp[bb][uu];
        float zf = zy[512]  + zp[bb][16 + uu];
        float zg = zy[1024] + zp[bb][32 + uu];
        float zo = zy[1536] + zp[bb][48 + uu];
        float ig = 1.f / (1.f + expf(-zi));
        float fg = 1.f / (1.f + expf(-zf));
        float gg = tanhf(zg);
        float og = 1.f / (1.f + expf(-zo));
        c = fg * c + ig * gg;
        float hv2 = og * tanhf(c);
        AT_ST(&h1rot[(size_t)(t + 1) * 16384 + (size_t)b * 512 + u], hv2);
      }
      group_bar(own, t + 1, wgid);
    }
  } else {
    for (int t = 0; t < T_; ++t) {
      // wait layer1's h1 output for this step (slot t+1 = hs1[t])
      g_wait32(in1, t + 1);
      // W-GEMV from global (independent of h2) — hides own-barrier RTT
      float accW = 0.f;
      {
        const float4* W4 = (const float4*)(W2T + (size_t)zcol * 512);
        const float4* H1 = (const float4*)(h1rot + (size_t)(t + 1) * 16384 +
                                           (size_t)(8 * g + b_l) * 512);
#pragma unroll 4
        for (int i = 0; i < 128; ++i) {
          float4 wv = W4[i];
          float4 hv = H1[i];
          accW = fmaf(hv.x, wv.x, accW); accW = fmaf(hv.y, wv.y, accW);
          accW = fmaf(hv.z, wv.z, accW); accW = fmaf(hv.w, wv.w, accW);
        }
      }
      if (t) g_wait32(own, t);        // h2(t) complete (posted end of t-1)
      // stage h2(t)
      {
        const float4* hb4 =
            (const float4*)(h2rot + (size_t)t * 16384 + (size_t)(8 * g) * 512);
#pragma unroll
        for (int it = 0; it < 2; ++it) {
          int idx = it * 512 + tid;
          float4 v = hb4[idx];
          *(float4*)(h_st + (idx >> 7) * 516 + (idx & 127) * 4) = v;
        }
      }
      __syncthreads();
      {
        const float4* H4 = (const float4*)(h_st + b_l * 516);
        const float4* Rr = (const float4*)(R_s + col * 516);
        float acc = accW;
#pragma unroll 8
        for (int i = 0; i < 128; ++i) {
          float4 hv = H4[i];
          float4 rv = Rr[i];
          acc = fmaf(hv.x, rv.x, acc); acc = fmaf(hv.y, rv.y, acc);
          acc = fmaf(hv.z, rv.z, acc); acc = fmaf(hv.w, rv.w, acc);
        }
        zp[b_l][col] = acc;
      }
      __syncthreads();
      if (tid < 128) {
        const int bb = tid >> 4, uu = tid & 15;
        const int b = 8 * g + bb, u = u0 + uu;
        float zi = b2[u]        + zp[bb][uu];
        float zf = b2[512 + u]  + zp[bb][16 + uu];
        float zg = b2[1024 + u] + zp[bb][32 + uu];
        float zo = b2[1536 + u] + zp[bb][48 + uu];
        float ig = 1.f / (1.f + expf(-zi));
        float fg = 1.f / (1.f + expf(-zf));
        float gg = tanhf(zg);
        float og = 1.f / (1.f + expf(-zo));
        c = fg * c + ig * gg;
        float hv2 = og * tanhf(c);
        AT_ST(&h2rot[(size_t)(t + 1) * 16384 + (size_t)b * 512 + u], hv2);
        if (t == T_ - 1) hT[(size_t)b * 512 + u] = hv2;
      }
      g_arrive(own, t + 1, wgid);
      // own-flag RTT elapses during next iteration's g_wait32(in1)+W-GEMV.
    }
  }
}

// ---------------- decoder ----------------
__global__ __launch_bounds__(64) void final_k(
    const float* __restrict__ hT, const float* __restrict__ Wd,
    const float* __restrict__ bd, float* __restrict__ out) {
  const int b = blockIdx.x;
  const int v = threadIdx.x;
  float acc = (v < V_) ? bd[v] : -INFINITY;
  if (v < V_) {
    for (int k = 0; k < U_; ++k)
      acc = fmaf(hT[(size_t)b * U_ + k], Wd[(size_t)k * V_ + v], acc);
  }
  float m = acc;
#pragma unroll
  for (int off = 32; off; off >>= 1) m = fmaxf(m, __shfl_down(m, off));
  m = __shfl(m, 0);
  float e = (v < V_) ? expf(acc - m) : 0.f;
  float s = e;
#pragma unroll
  for (int off = 32; off; off >>= 1) s += __shfl_down(s, off);
  s = __shfl(s, 0);
  if (v < V_) out[(size_t)b * V_ + v] = e / s;
}

extern "C" void kernel_launch(void* const* d_in, const int* in_sizes, int n_in,
                              void* d_out, int out_size, void* d_ws, size_t ws_size,
                              hipStream_t stream) {
  const float* x   = (const float*)d_in[0];
  const float* y   = (const float*)d_in[1];
  const float* W_a = (const float*)d_in[2];
  const float* R_a = (const float*)d_in[3];
  const float* b_a = (const float*)d_in[4];
  const float* W1  = (const float*)d_in[5];
  const float* R1  = (const float*)d_in[6];
  const float* b1  = (const float*)d_in[7];
  const float* W2  = (const float*)d_in[8];
  const float* R2  = (const float*)d_in[9];
  const float* b2  = (const float*)d_in[10];
  const float* Wd  = (const float*)d_in[11];
  const float* bd  = (const float*)d_in[12];
  float* out = (float*)d_out;

  float* ZBUF  = (float*)d_ws;                   // 8388608 f
  float* SEQ   = ZBUF + (size_t)8388608;         // 2097152 f (ctxs)
  float* RT    = SEQ + (size_t)2097152;          // 1048576 f
  float* HROT  = RT + (size_t)1048576;           // 129*16384 (attn h / h1rot)
  float* HNROT = HROT + (size_t)2113536;         // 128*16384 (attn hn / W2T)
  float* SMAX  = HNROT + (size_t)2097152;        // 256
  float* SSUM  = SMAX + 256;                     // 256
  float* CTXP  = SSUM + 256;                     // 131072
  float* HT    = CTXP + 131072;                  // 16384
  float* H2ROT = HT + 16384;                     // 129*16384 = 2113536 f
  unsigned* BAR = (unsigned*)(H2ROT + 2113536);

  float* W2T = HNROT;                            // reuse after attn completes

  // per kernel-instance flag regions: 8 groups x 32 flags x FSTR
  const int REGION = 8 * 32 * FSTR;              // 8192 u32
  unsigned* FLG_A = BAR;
  unsigned* FLG_1 = BAR + REGION;
  unsigned* FLG_2 = BAR + 2 * REGION;

  const int attn_lds  = (512 * 65 + 4 * 516) * 4;   // 141376 B
  const int fused_lds = (64 * 516 + 8 * 516) * 4;   // 148608 B
  hipFuncSetAttribute((const void*)attn_coop,
                      hipFuncAttributeMaxDynamicSharedMemorySize, attn_lds);
  hipFuncSetAttribute((const void*)lstm_fused,
                      hipFuncAttributeMaxDynamicSharedMemorySize, fused_lds);

  dim3 ggrid(2, 512);
  hipMemsetAsync(BAR, 0, 3 * REGION * 4, stream);

  gemm_k512<<<ggrid, 256, 0, stream>>>(y, W_a, b_a, ZBUF);
  transpose_R<<<dim3(32, 8), 256, 0, stream>>>(R_a, RT);
  hipMemsetAsync(HROT, 0, 16384 * 4, stream);          // attn h[0] = 0
  attn_coop<<<NWG, 512, attn_lds, stream>>>(x, ZBUF, RT, SEQ, HROT, HNROT,
                                            SMAX, SSUM, CTXP, FLG_A);
  gemm_k512<<<ggrid, 256, 0, stream>>>(SEQ, W1, b1, ZBUF);    // ZY1
  transpose_R<<<dim3(32, 8), 256, 0, stream>>>(W2, W2T);      // after attn!
  hipMemsetAsync(HROT, 0, 16384 * 4, stream);          // h1[0] = 0
  hipMemsetAsync(H2ROT, 0, 16384 * 4, stream);         // h2[0] = 0
  lstm_fused<<<NWG, 512, fused_lds, stream>>>(ZBUF, R1, R2, W2T, b2,
                                              HROT, H2ROT, HT, FLG_1, FLG_2);
  final_k<<<B_, 64, 0, stream>>>(HT, Wd, bd, out);
}

// Round 4
// 3989.807 us; speedup vs baseline: 2.7703x; 1.9237x over previous
//
#include <hip/hip_runtime.h>
#include <math.h>

// Speller round 11: v7 restored verbatim + one local attn optimization.
//   v8 (redundant combine), v9 (2 WG/CU), v10 (lstm fusion) all regressed:
//   the v7 structure — 3-exchange attn, 1-exchange lstm, 1 WG/CU, 32-WG
//   groups, kh-split GEMVs — is a local optimum vs every structural
//   perturbation. v11 keeps it exactly and only rewrites the attn scores
//   phase: hn hoisted into 8 registers read once per step straight from the
//   rotating hnbuf slot (same virgin-line cached pattern as the verified
//   staging burst), removing the hn_s LDS stage, one __syncthreads, and
//   ~56 LDS reads/thread/step.

#define U_   512
#define S_   512
#define T_   128
#define B_   32
#define G4   2048
#define V_   46
#define NWG  256
#define FSTR 32            // flag stride in u32 = 128 B

#define AT_LD(p)     __hip_atomic_load((p), __ATOMIC_RELAXED, __HIP_MEMORY_SCOPE_AGENT)
#define AT_ST(p, v)  __hip_atomic_store((p), (v), __ATOMIC_RELAXED, __HIP_MEMORY_SCOPE_AGENT)

// 1-hop barrier over the 32 WGs of this group. gflags = 32 padded slots.
__device__ __forceinline__ void group_bar(unsigned* gflags, unsigned seq) {
  __syncthreads();   // all waves' stores drained (vmcnt) before arrival
  const int tid = threadIdx.x;
  if (tid < 32) {
    if (tid == 0)
      AT_ST(&gflags[(blockIdx.x & 31) * FSTR], seq);
    while (!__all(AT_LD(&gflags[tid * FSTR]) >= seq))
      __builtin_amdgcn_s_sleep(1);
  }
  __syncthreads();
}

// ---------------- GEMM: Z[M,2048] = A[M,512] @ W[512,2048] + b ----------------
__global__ __launch_bounds__(256) void gemm_k512(
    const float* __restrict__ A, const float* __restrict__ W,
    const float* __restrict__ b, float* __restrict__ Z) {
  const int tid = threadIdx.x;
  const int j = blockIdx.x * 1024 + tid * 4;
  const int i0 = blockIdx.y * 8;
  float4 bj = *(const float4*)(b + j);
  float4 acc[8];
#pragma unroll
  for (int r = 0; r < 8; ++r) acc[r] = bj;
  const float* Arow = A + (size_t)i0 * U_;
  for (int k = 0; k < U_; ++k) {
    float4 w = *(const float4*)(W + (size_t)k * G4 + j);
#pragma unroll
    for (int r = 0; r < 8; ++r) {
      float a = Arow[(size_t)r * U_ + k];
      acc[r].x = fmaf(a, w.x, acc[r].x);
      acc[r].y = fmaf(a, w.y, acc[r].y);
      acc[r].z = fmaf(a, w.z, acc[r].z);
      acc[r].w = fmaf(a, w.w, acc[r].w);
    }
  }
#pragma unroll
  for (int r = 0; r < 8; ++r)
    *(float4*)(Z + (size_t)(i0 + r) * G4 + j) = acc[r];
}

// ---------------- transpose R[512][2048] -> RT[2048][512] ----------------
__global__ __launch_bounds__(256) void transpose_R(
    const float* __restrict__ R, float* __restrict__ RT) {
  __shared__ float tile[64][65];
  const int c0 = blockIdx.x * 64, k0 = blockIdx.y * 64;
  const int tc = threadIdx.x & 63, tr = threadIdx.x >> 6;
  for (int r = tr; r < 64; r += 4)
    tile[r][tc] = R[(size_t)(k0 + r) * G4 + c0 + tc];
  __syncthreads();
  for (int r = tr; r < 64; r += 4)
    RT[(size_t)(c0 + r) * 512 + k0 + tc] = tile[tc][r];
}

// ---------------- attention LSTM: 8 groups x 32 WGs, 4 batches/group ------
// dyn LDS: x_s [512][65] + h_st [4][516]  = 141376 B
// hbuf: rotating [T+1][32][512]; hnbuf: rotating [T][32][512]
__global__ __launch_bounds__(512) void attn_coop(
    const float* __restrict__ x, const float* __restrict__ ZY,
    const float* __restrict__ RT, float* __restrict__ ctxs,
    float* hbuf, float* hnbuf, float* smax, float* ssumg,
    float* ctxpart, unsigned* flags) {
  extern __shared__ float dyn[];
  float* x_s  = dyn;                 // [u][65], conflict-free
  float* h_st = dyn + 512 * 65;      // [b_l][516]
  __shared__ float zp[4][64][2];
  __shared__ float p_s[64];
  __shared__ float ctx_s[64];

  const int tid = threadIdx.x;
  const int bid = blockIdx.x;
  const int g    = bid >> 5;
  const int wgid = bid & 31;
  const int u0   = wgid * 16;
  // GEMV role mapping: 64 cols x 4 batches x 2 k-halves
  const int kh  = tid & 1;
  const int b_l = (tid >> 1) & 3;
  const int col = tid >> 3;                       // 0..63
  const int zcol = (col >> 4) * 512 + u0 + (col & 15);
  // attention role mapping
  const int b_att = 4 * g + (wgid >> 3);
  const int sc = wgid & 7;
  unsigned* gflags = flags + g * 32 * FSTR;

  for (int idx = tid; idx < 64 * 512; idx += 512) {
    int sl = idx >> 9, u = idx & 511;
    x_s[u * 65 + sl] = x[((size_t)b_att * S_ + sc * 64 + sl) * U_ + u];
  }
  float c = 0.f, hn_reg = 0.f;
  unsigned seq = 0;
  __syncthreads();

  for (int t = 0; t < T_; ++t) {
    // ---- stage h slot t (cached float4 burst: virgin lines -> IF$) ----
    {
      const float4* hb4 =
          (const float4*)(hbuf + (size_t)t * 16384 + 4 * g * 512);
      float4 v = hb4[tid];
      *(float4*)(h_st + (tid >> 7) * 516 + (tid & 127) * 4) = v;
    }
    __syncthreads();
    // ---- GEMV: z-partial from h(LDS) x RT(L2) ----
    {
      const float4* H4 = (const float4*)(h_st + b_l * 516 + kh * 256);
      const float4* R4 = (const float4*)(RT + (size_t)zcol * 512 + kh * 256);
      float acc = 0.f;
#pragma unroll 8
      for (int i = 0; i < 64; ++i) {
        float4 hv = H4[i];
        float4 rv = R4[i];
        acc = fmaf(hv.x, rv.x, acc); acc = fmaf(hv.y, rv.y, acc);
        acc = fmaf(hv.z, rv.z, acc); acc = fmaf(hv.w, rv.w, acc);
      }
      zp[b_l][col][kh] = acc;
    }
    __syncthreads();
    if (tid < 64) {
      const int bb = tid >> 4, uu = tid & 15;
      const int b = 4 * g + bb, u = u0 + uu;
      const float* zy = ZY + ((size_t)b * T_ + t) * G4 + u;
      float zi = zy[0]    + zp[bb][uu][0]      + zp[bb][uu][1];
      float zf = zy[512]  + zp[bb][16 + uu][0] + zp[bb][16 + uu][1];
      float zg = zy[1024] + zp[bb][32 + uu][0] + zp[bb][32 + uu][1];
      float zo = zy[1536] + zp[bb][48 + uu][0] + zp[bb][48 + uu][1];
      float ig = 1.f / (1.f + expf(-zi));
      float fg = 1.f / (1.f + expf(-zf));
      float gg = tanhf(zg);
      float og = 1.f / (1.f + expf(-zo));
      c = fg * c + ig * gg;
      hn_reg = og * tanhf(c);
      AT_ST(&hnbuf[(size_t)t * 16384 + b * 512 + u], hn_reg);
    }
    group_bar(gflags, ++seq);

    // ---- scores (hn in 8 regs, read once from rotating hnbuf slot),
    //      local softmax, ctx partials ----
    {
      const int wv = tid >> 6, ln = tid & 63;
      const float* hnb = hnbuf + (size_t)t * 16384 + b_att * 512;
      float hreg[8];
#pragma unroll
      for (int k = 0; k < 8; ++k) hreg[k] = hnb[ln + 64 * k];
      for (int si = 0; si < 8; ++si) {
        const int sl = wv * 8 + si;
        float a = 0.f;
#pragma unroll
        for (int k = 0; k < 8; ++k)
          a = fmaf(hreg[k], x_s[(ln + 64 * k) * 65 + sl], a);
#pragma unroll
        for (int off = 32; off; off >>= 1) a += __shfl_down(a, off);
        if (ln == 0) p_s[sl] = a;
      }
    }
    __syncthreads();
    if (tid < 64) {
      float v = p_s[tid];
      float m = v;
#pragma unroll
      for (int off = 32; off; off >>= 1) m = fmaxf(m, __shfl_down(m, off));
      m = __shfl(m, 0);
      float ex = expf(v - m);
      p_s[tid] = ex;
      float sm = ex;
#pragma unroll
      for (int off = 32; off; off >>= 1) sm += __shfl_down(sm, off);
      if (tid == 0) {
        AT_ST(&smax[b_att * 8 + sc], m);
        AT_ST(&ssumg[b_att * 8 + sc], sm);
      }
    }
    __syncthreads();
    {
      float a = 0.f;
      const float* xr = x_s + tid * 65;
#pragma unroll 8
      for (int s = 0; s < 64; ++s) a = fmaf(p_s[s], xr[s], a);
      AT_ST(&ctxpart[((size_t)b_att * 8 + sc) * 512 + tid], a);
    }
    group_bar(gflags, ++seq);

    // ---- combine slices (parallel over 512 thr: pair x j, sc1 gathers) ----
    {
      const int j = tid & 7;
      const int pair = tid >> 3;            // 0..63 == gates-thread index
      const int bb = pair >> 4, uu = pair & 15;
      const int b = 4 * g + bb, u = u0 + uu;
      float lm = AT_LD(&smax[b * 8 + j]);
      float ss = AT_LD(&ssumg[b * 8 + j]);
      float cp = AT_LD(&ctxpart[((size_t)b * 8 + j) * 512 + u]);
      float gm = lm;
#pragma unroll
      for (int off = 1; off < 8; off <<= 1)
        gm = fmaxf(gm, __shfl_xor(gm, off));
      float w = expf(lm - gm);
      float st = ss * w, cs = cp * w;
#pragma unroll
      for (int off = 1; off < 8; off <<= 1) {
        st += __shfl_xor(st, off);
        cs += __shfl_xor(cs, off);
      }
      if (j == 0) ctx_s[pair] = cs / st;
    }
    __syncthreads();
    if (tid < 64) {
      const int bb = tid >> 4, uu = tid & 15;
      const int b = 4 * g + bb, u = u0 + uu;
      float ctxv = ctx_s[tid];
      c += ctxv;
      float hcar = hn_reg + ctxv;
      AT_ST(&hbuf[(size_t)(t + 1) * 16384 + b * 512 + u], hcar);
      ctxs[((size_t)b * T_ + t) * U_ + u] = ctxv;
    }
    group_bar(gflags, ++seq);
  }
}

// ---------------- plain LSTM: 8 groups x 32 WGs ----------------
// dyn LDS: R_s [64][516] + h_st [4][516] = 140352 B; hbuf rotating
__global__ __launch_bounds__(512) void lstm_coop(
    const float* __restrict__ Zin, const float* __restrict__ R,
    float* __restrict__ seq_out, float* __restrict__ last_out,
    float* hbuf, unsigned* flags) {
  extern __shared__ float dyn[];
  float* R_s  = dyn;                 // [col][516]
  float* h_st = dyn + 64 * 516;      // [b_l][516]
  __shared__ float zp[4][64][2];
  const int tid = threadIdx.x;
  const int bid = blockIdx.x;
  const int g    = bid >> 5;
  const int wgid = bid & 31;
  const int u0   = wgid * 16;
  const int kh  = tid & 1;
  const int b_l = (tid >> 1) & 3;
  const int col = tid >> 3;
  unsigned* gflags = flags + g * 32 * FSTR;

  // one-time R slice -> LDS (transposed to [col][k])
  for (int idx = tid; idx < 64 * 512; idx += 512) {
    int cc = idx & 63, kk = idx >> 6;
    R_s[cc * 516 + kk] = R[(size_t)kk * G4 + (cc >> 4) * 512 + u0 + (cc & 15)];
  }
  float c = 0.f;
  unsigned seq = 0;
  __syncthreads();

  for (int t = 0; t < T_; ++t) {
    {
      const float4* hb4 =
          (const float4*)(hbuf + (size_t)t * 16384 + 4 * g * 512);
      float4 v = hb4[tid];
      *(float4*)(h_st + (tid >> 7) * 516 + (tid & 127) * 4) = v;
    }
    __syncthreads();
    {
      const float4* H4 = (const float4*)(h_st + b_l * 516 + kh * 256);
      const float4* R4 = (const float4*)(R_s + col * 516 + kh * 256);
      float acc = 0.f;
#pragma unroll 8
      for (int i = 0; i < 64; ++i) {
        float4 hv = H4[i];
        float4 rv = R4[i];
        acc = fmaf(hv.x, rv.x, acc); acc = fmaf(hv.y, rv.y, acc);
        acc = fmaf(hv.z, rv.z, acc); acc = fmaf(hv.w, rv.w, acc);
      }
      zp[b_l][col][kh] = acc;
    }
    __syncthreads();
    if (tid < 64) {
      const int bb = tid >> 4, uu = tid & 15;
      const int b = 4 * g + bb, u = u0 + uu;
      const float* zy = Zin + ((size_t)b * T_ + t) * G4 + u;
      float zi = zy[0]    + zp[bb][uu][0]      + zp[bb][uu][1];
      float zf = zy[512]  + zp[bb][16 + uu][0] + zp[bb][16 + uu][1];
      float zg = zy[1024] + zp[bb][32 + uu][0] + zp[bb][32 + uu][1];
      float zo = zy[1536] + zp[bb][48 + uu][0] + zp[bb][48 + uu][1];
      float ig = 1.f / (1.f + expf(-zi));
      float fg = 1.f / (1.f + expf(-zf));
      float gg = tanhf(zg);
      float og = 1.f / (1.f + expf(-zo));
      c = fg * c + ig * gg;
      float hv2 = og * tanhf(c);
      AT_ST(&hbuf[(size_t)(t + 1) * 16384 + b * 512 + u], hv2);
      if (seq_out) seq_out[((size_t)b * T_ + t) * U_ + u] = hv2;
      if (last_out && t == T_ - 1) last_out[b * U_ + u] = hv2;
    }
    group_bar(gflags, ++seq);
  }
}

// ---------------- decoder ----------------
__global__ __launch_bounds__(64) void final_k(
    const float* __restrict__ hT, const float* __restrict__ Wd,
    const float* __restrict__ bd, float* __restrict__ out) {
  const int b = blockIdx.x;
  const int v = threadIdx.x;
  float acc = (v < V_) ? bd[v] : -INFINITY;
  if (v < V_) {
    for (int k = 0; k < U_; ++k)
      acc = fmaf(hT[(size_t)b * U_ + k], Wd[(size_t)k * V_ + v], acc);
  }
  float m = acc;
#pragma unroll
  for (int off = 32; off; off >>= 1) m = fmaxf(m, __shfl_down(m, off));
  m = __shfl(m, 0);
  float e = (v < V_) ? expf(acc - m) : 0.f;
  float s = e;
#pragma unroll
  for (int off = 32; off; off >>= 1) s += __shfl_down(s, off);
  s = __shfl(s, 0);
  if (v < V_) out[(size_t)b * V_ + v] = e / s;
}

extern "C" void kernel_launch(void* const* d_in, const int* in_sizes, int n_in,
                              void* d_out, int out_size, void* d_ws, size_t ws_size,
                              hipStream_t stream) {
  const float* x   = (const float*)d_in[0];
  const float* y   = (const float*)d_in[1];
  const float* W_a = (const float*)d_in[2];
  const float* R_a = (const float*)d_in[3];
  const float* b_a = (const float*)d_in[4];
  const float* W1  = (const float*)d_in[5];
  const float* R1  = (const float*)d_in[6];
  const float* b1  = (const float*)d_in[7];
  const float* W2  = (const float*)d_in[8];
  const float* R2  = (const float*)d_in[9];
  const float* b2  = (const float*)d_in[10];
  const float* Wd  = (const float*)d_in[11];
  const float* bd  = (const float*)d_in[12];
  float* out = (float*)d_out;

  float* ZBUF  = (float*)d_ws;                   // 8388608 f
  float* SEQ   = ZBUF + (size_t)8388608;         // 2097152 f
  float* RT    = SEQ + (size_t)2097152;          // 1048576 f
  float* HROT  = RT + (size_t)1048576;           // 129*16384 = 2113536 f
  float* HNROT = HROT + (size_t)2113536;         // 128*16384 = 2097152 f
  float* SMAX  = HNROT + (size_t)2097152;        // 256
  float* SSUM  = SMAX + 256;                     // 256
  float* CTXP  = SSUM + 256;                     // 131072
  float* HT    = CTXP + 131072;                  // 16384
  unsigned* BAR = (unsigned*)(HT + 16384);

  // per kernel-instance: 8 groups x 32 flags x FSTR
  const int REGION = 8 * 32 * FSTR;              // 8192 u32
  unsigned* FLG_A = BAR;
  unsigned* FLG_1 = BAR + REGION;
  unsigned* FLG_2 = BAR + 2 * REGION;

  const int attn_lds = (512 * 65 + 4 * 516) * 4;    // 141376 B
  const int lstm_lds = (64 * 516 + 4 * 516) * 4;    // 140352 B
  hipFuncSetAttribute((const void*)attn_coop,
                      hipFuncAttributeMaxDynamicSharedMemorySize, attn_lds);
  hipFuncSetAttribute((const void*)lstm_coop,
                      hipFuncAttributeMaxDynamicSharedMemorySize, lstm_lds);

  dim3 ggrid(2, 512);
  hipMemsetAsync(BAR, 0, 3 * REGION * 4, stream);

  gemm_k512<<<ggrid, 256, 0, stream>>>(y, W_a, b_a, ZBUF);
  transpose_R<<<dim3(32, 8), 256, 0, stream>>>(R_a, RT);
  hipMemsetAsync(HROT, 0, 16384 * 4, stream);          // h[0] = 0
  attn_coop<<<NWG, 512, attn_lds, stream>>>(x, ZBUF, RT, SEQ, HROT, HNROT,
                                            SMAX, SSUM, CTXP, FLG_A);
  gemm_k512<<<ggrid, 256, 0, stream>>>(SEQ, W1, b1, ZBUF);
  hipMemsetAsync(HROT, 0, 16384 * 4, stream);          // h1[0] = 0
  lstm_coop<<<NWG, 512, lstm_lds, stream>>>(ZBUF, R1, SEQ, nullptr, HROT,
                                            FLG_1);
  gemm_k512<<<ggrid, 256, 0, stream>>>(SEQ, W2, b2, ZBUF);
  hipMemsetAsync(HROT, 0, 16384 * 4, stream);          // h2[0] = 0
  lstm_coop<<<NWG, 512, lstm_lds, stream>>>(ZBUF, R2, nullptr, HT, HROT,
                                            FLG_2);
  final_k<<<B_, 64, 0, stream>>>(HT, Wd, bd, out);
}